// Round 3
// baseline (164.953 us; speedup 1.0000x reference)
//
#include <hip/hip_runtime.h>
#include <math.h>

#define NH 32
#define HD 128
#define BS 16
#define MAXB 64
#define HID 4096
#define NBATCH 16
#define QKV_R 12288
#define SCALE 0.08838834764831845f  // 1/sqrt(128)
#define TPC 128                     // tokens per chunk
#define NCHUNK 8                    // max chunks (MAXB*BS / TPC)

// y[b*R + r] = sum_j x[b*4096+j] * W[r*4096+j].
// 8 rows per block; wave w handles batches 4w..4w+3 (acc[8][4] in regs).
__global__ __launch_bounds__(256) void gemv16_v2(
    const float* __restrict__ x, const float* __restrict__ W,
    float* __restrict__ y, int R) {
  const int r0 = blockIdx.x * 8;
  const int tid = threadIdx.x;
  const int wave = tid >> 6, lane = tid & 63;
  const int b0 = wave * 4;

  float acc[8][4];
#pragma unroll
  for (int r = 0; r < 8; ++r)
#pragma unroll
    for (int bb = 0; bb < 4; ++bb) acc[r][bb] = 0.f;

#pragma unroll 2
  for (int it = 0; it < 16; ++it) {
    const int j = it * 256 + lane * 4;
    float4 wv[8];
#pragma unroll
    for (int r = 0; r < 8; ++r)
      wv[r] = *reinterpret_cast<const float4*>(&W[(size_t)(r0 + r) * 4096 + j]);
    float4 xv[4];
#pragma unroll
    for (int bb = 0; bb < 4; ++bb)
      xv[bb] = *reinterpret_cast<const float4*>(&x[(size_t)(b0 + bb) * 4096 + j]);
#pragma unroll
    for (int r = 0; r < 8; ++r)
#pragma unroll
      for (int bb = 0; bb < 4; ++bb)
        acc[r][bb] += wv[r].x * xv[bb].x + wv[r].y * xv[bb].y +
                      wv[r].z * xv[bb].z + wv[r].w * xv[bb].w;
  }

#pragma unroll
  for (int r = 0; r < 8; ++r)
#pragma unroll
    for (int bb = 0; bb < 4; ++bb) {
      float v = acc[r][bb];
#pragma unroll
      for (int off = 32; off; off >>= 1) v += __shfl_xor(v, off, 64);
      if (lane == 0) y[(size_t)(b0 + bb) * R + r0 + r] = v;
    }
}

// Flash-decoding chunk kernel. Grid: (B*NH, NCHUNK). Each block handles
// tokens [c*TPC, min((c+1)*TPC, ctx)) of (b,h), writes unnormalized partial
// o (128 floats) plus m (chunk max) and l (chunk expsum) to workspace.
// New k/v substituted at global token s == ctx-1.
__global__ __launch_bounds__(256) void attn_split(
    const float* __restrict__ qkv, const float* __restrict__ cs_cache,
    const float* __restrict__ kcache, const float* __restrict__ vcache,
    const int* __restrict__ pos_ids, const int* __restrict__ btab,
    const int* __restrict__ ctx_len, float* __restrict__ o_part,
    float* __restrict__ m_part, float* __restrict__ l_part) {
  const int bh = blockIdx.x;
  const int b = bh >> 5, h = bh & 31;
  const int c = blockIdx.y;
  const int ctx = ctx_len[b];
  const int t0 = c * TPC;
  if (t0 >= ctx) return;
  const int tend = min(t0 + TPC, ctx);
  const int n = tend - t0;
  const int last = ctx - 1;

  const int tid = threadIdx.x;
  const int wave = tid >> 6, lane = tid & 63;
  const int grp = lane >> 3, sub = lane & 7;
  const int gid = wave * 8 + grp;  // 0..31 token groups

  __shared__ float q_rot[HD], k_rot[HD], v_new[HD];
  __shared__ float scores[TPC];
  __shared__ int blk_base[TPC / BS];
  __shared__ float redm[4], reds[4];
  __shared__ float ow[4][HD];

  const int pos = pos_ids[b];
  const float* qp = qkv + (size_t)b * QKV_R + h * HD;
  const float* kp = qp + 4096;
  const float* vp = qp + 8192;
  const float* cs = cs_cache + (size_t)pos * HD;

  if (tid < 64) {
    const float co = cs[tid], si = cs[64 + tid];
    const float a1 = qp[tid], a2 = qp[tid + 64];
    q_rot[tid] = a1 * co - a2 * si;
    q_rot[tid + 64] = a2 * co + a1 * si;
    const float b1 = kp[tid], b2 = kp[tid + 64];
    k_rot[tid] = b1 * co - b2 * si;
    k_rot[tid + 64] = b2 * co + b1 * si;
  } else if (tid < 192) {
    v_new[tid - 64] = vp[tid - 64];
  } else if (tid < 192 + TPC / BS) {
    const int i = tid - 192;
    const int bt_idx = (t0 >> 4) + i;
    blk_base[i] = (bt_idx < MAXB) ? btab[b * MAXB + bt_idx] : 0;
  }
  __syncthreads();

  float4 qf[4];
#pragma unroll
  for (int i = 0; i < 4; ++i)
    qf[i] = *reinterpret_cast<const float4*>(&q_rot[sub * 4 + i * 32]);

  // Pass 1: scores for this chunk
  for (int t = t0 + gid; t < tend; t += 32) {
    float4 kv[4];
    if (t == last) {
#pragma unroll
      for (int i = 0; i < 4; ++i)
        kv[i] = *reinterpret_cast<const float4*>(&k_rot[sub * 4 + i * 32]);
    } else {
      const int blk = blk_base[(t - t0) >> 4];
      const float* kr = kcache + ((((size_t)blk << 4) + (t & 15)) * NH + h) * HD;
#pragma unroll
      for (int i = 0; i < 4; ++i)
        kv[i] = *reinterpret_cast<const float4*>(&kr[sub * 4 + i * 32]);
    }
    float d0 = kv[0].x * qf[0].x + kv[0].y * qf[0].y + kv[0].z * qf[0].z + kv[0].w * qf[0].w;
    float d1 = kv[1].x * qf[1].x + kv[1].y * qf[1].y + kv[1].z * qf[1].z + kv[1].w * qf[1].w;
    float d2 = kv[2].x * qf[2].x + kv[2].y * qf[2].y + kv[2].z * qf[2].z + kv[2].w * qf[2].w;
    float d3 = kv[3].x * qf[3].x + kv[3].y * qf[3].y + kv[3].z * qf[3].z + kv[3].w * qf[3].w;
    float d = (d0 + d1) + (d2 + d3);
    d += __shfl_xor(d, 1, 64);
    d += __shfl_xor(d, 2, 64);
    d += __shfl_xor(d, 4, 64);
    if (sub == 0) scores[t - t0] = d * SCALE;
  }
  __syncthreads();

  // Chunk max (n <= 128 entries)
  float m = (tid < n) ? scores[tid] : -1e30f;
#pragma unroll
  for (int off = 32; off; off >>= 1) m = fmaxf(m, __shfl_xor(m, off, 64));
  if (lane == 0) redm[wave] = m;
  __syncthreads();
  m = fmaxf(fmaxf(redm[0], redm[1]), fmaxf(redm[2], redm[3]));

  // Exp + sum
  float ssum = 0.f;
  if (tid < n) {
    const float e = expf(scores[tid] - m);
    scores[tid] = e;
    ssum = e;
  }
#pragma unroll
  for (int off = 32; off; off >>= 1) ssum += __shfl_xor(ssum, off, 64);
  if (lane == 0) reds[wave] = ssum;
  __syncthreads();
  const float l = reds[0] + reds[1] + reds[2] + reds[3];

  // Pass 2: P @ V (unnormalized)
  float4 oacc[4];
#pragma unroll
  for (int i = 0; i < 4; ++i) oacc[i] = make_float4(0.f, 0.f, 0.f, 0.f);

  for (int t = t0 + gid; t < tend; t += 32) {
    const float p = scores[t - t0];
    float4 vv[4];
    if (t == last) {
#pragma unroll
      for (int i = 0; i < 4; ++i)
        vv[i] = *reinterpret_cast<const float4*>(&v_new[sub * 4 + i * 32]);
    } else {
      const int blk = blk_base[(t - t0) >> 4];
      const float* vr = vcache + ((((size_t)blk << 4) + (t & 15)) * NH + h) * HD;
#pragma unroll
      for (int i = 0; i < 4; ++i)
        vv[i] = *reinterpret_cast<const float4*>(&vr[sub * 4 + i * 32]);
    }
#pragma unroll
    for (int i = 0; i < 4; ++i) {
      oacc[i].x += p * vv[i].x;
      oacc[i].y += p * vv[i].y;
      oacc[i].z += p * vv[i].z;
      oacc[i].w += p * vv[i].w;
    }
  }

#pragma unroll
  for (int i = 0; i < 4; ++i) {
#pragma unroll
    for (int off = 8; off <= 32; off <<= 1) {
      oacc[i].x += __shfl_xor(oacc[i].x, off, 64);
      oacc[i].y += __shfl_xor(oacc[i].y, off, 64);
      oacc[i].z += __shfl_xor(oacc[i].z, off, 64);
      oacc[i].w += __shfl_xor(oacc[i].w, off, 64);
    }
  }
  if (grp == 0) {
#pragma unroll
    for (int i = 0; i < 4; ++i)
      *reinterpret_cast<float4*>(&ow[wave][sub * 4 + i * 32]) = oacc[i];
  }
  __syncthreads();
  if (tid < HD) {
    const float o = ow[0][tid] + ow[1][tid] + ow[2][tid] + ow[3][tid];
    o_part[((size_t)bh * NCHUNK + c) * HD + tid] = o;
    if (tid == 0) {
      m_part[bh * NCHUNK + c] = m;
      l_part[bh * NCHUNK + c] = l;
    }
  }
}

// Combine partials: one block per (b,h), 128 threads (one per dim).
__global__ __launch_bounds__(128) void attn_combine(
    const float* __restrict__ o_part, const float* __restrict__ m_part,
    const float* __restrict__ l_part, const int* __restrict__ ctx_len,
    float* __restrict__ attn_out) {
  const int bh = blockIdx.x;
  const int b = bh >> 5, h = bh & 31;
  const int ctx = ctx_len[b];
  const int nc = (ctx + TPC - 1) / TPC;
  const int d = threadIdx.x;

  float M = -1e30f;
  for (int c = 0; c < nc; ++c) M = fmaxf(M, m_part[bh * NCHUNK + c]);
  float L = 0.f, o = 0.f;
  for (int c = 0; c < nc; ++c) {
    const float sc = expf(m_part[bh * NCHUNK + c] - M);
    L += l_part[bh * NCHUNK + c] * sc;
    o += o_part[((size_t)bh * NCHUNK + c) * HD + d] * sc;
  }
  attn_out[(size_t)b * HID + h * HD + d] = o / L;
}

extern "C" void kernel_launch(void* const* d_in, const int* in_sizes, int n_in,
                              void* d_out, int out_size, void* d_ws, size_t ws_size,
                              hipStream_t stream) {
  const float* hidden = (const float*)d_in[0];   // (16,1,4096)
  const float* qkv_w  = (const float*)d_in[1];   // (12288,4096)
  const float* out_w  = (const float*)d_in[2];   // (4096,4096)
  const float* cs     = (const float*)d_in[3];   // (2048,128)
  const float* kc     = (const float*)d_in[4];   // (1024,16,32,128)
  const float* vc     = (const float*)d_in[5];   // (1024,16,32,128)
  const int* pos      = (const int*)d_in[6];     // (16,1)
  const int* bt       = (const int*)d_in[7];     // (16,64)
  // d_in[8] = slots (unused: substitution at s == ctx-1)
  const int* cl       = (const int*)d_in[9];     // (16,)
  float* out = (float*)d_out;                    // (16,1,4096)

  float* ws_qkv  = (float*)d_ws;                       // 16*12288
  float* ws_attn = ws_qkv + NBATCH * QKV_R;            // 16*4096
  float* ws_op   = ws_attn + NBATCH * HID;             // 512*8*128
  float* ws_m    = ws_op + (size_t)NBATCH * NH * NCHUNK * HD;  // 512*8
  float* ws_l    = ws_m + NBATCH * NH * NCHUNK;        // 512*8

  gemv16_v2<<<QKV_R / 8, 256, 0, stream>>>(hidden, qkv_w, ws_qkv, QKV_R);
  attn_split<<<dim3(NBATCH * NH, NCHUNK), 256, 0, stream>>>(
      ws_qkv, cs, kc, vc, pos, bt, cl, ws_op, ws_m, ws_l);
  attn_combine<<<NBATCH * NH, 128, 0, stream>>>(ws_op, ws_m, ws_l, cl, ws_attn);
  gemv16_v2<<<HID / 8, 256, 0, stream>>>(ws_attn, out_w, out, HID);
}